// Round 6
// baseline (2375.916 us; speedup 1.0000x reference)
//
#include <hip/hip_runtime.h>

// EdgeConvEncoder R6:
//  - scatter writes paired int2 (src,dst) -> half the scattered cachelines
//  - edge kernel: thread = (8-edge dst-run, head); ctx accumulated in
//    registers, flushed at dst boundaries. No LDS, no barriers, no segred.
//  - node-level GEMMs (Y1 = X@(Wtop-Wbot)+b, Y2 = X@Wbot) as R5.

typedef short bf16x8 __attribute__((ext_vector_type(8)));
typedef float f32x4 __attribute__((ext_vector_type(4)));

__device__ __forceinline__ unsigned short f2bf(float f) {
  unsigned int u = __float_as_uint(f);
  u += 0x7FFFu + ((u >> 16) & 1u);  // round-to-nearest-even
  return (unsigned short)(u >> 16);
}
__device__ __forceinline__ float b2f(short s) {
  return __uint_as_float(((unsigned)(unsigned short)s) << 16);
}

// ---------------- weight packing: 6 matrices (W1=top-bot x3, W2=bot x3) ----
__global__ void pack_weights6(const float* __restrict__ wq, const float* __restrict__ wk,
                              const float* __restrict__ wv, unsigned short* __restrict__ dst,
                              int IN, int O, float kscale) {
  int id = blockIdx.x * blockDim.x + threadIdx.x;
  int kchunks = IN >> 5, nchunks = O >> 4;
  int total = 6 * nchunks * kchunks * 64;
  if (id >= total) return;
  int lane = id & 63;
  int frag = id >> 6;
  int kc = frag % kchunks;
  int nc = (frag / kchunks) % nchunks;
  int mat = frag / (kchunks * nchunks);
  const float* w = (mat % 3 == 0) ? wq : (mat % 3 == 1) ? wk : wv;
  float mul = (mat % 3 == 1) ? kscale : 1.0f;
  int n = nc * 16 + (lane & 15);
  int k0 = kc * 32 + (lane >> 4) * 8;
  unsigned short tmp[8];
#pragma unroll
  for (int j = 0; j < 8; ++j) {
    int row = k0 + j;
    float bot = w[(size_t)(IN + row) * O + n];
    float val = (mat < 3) ? (w[(size_t)row * O + n] - bot) : bot;
    tmp[j] = f2bf(val * mul);
  }
  uint4 o;
  o.x = (unsigned)tmp[0] | ((unsigned)tmp[1] << 16);
  o.y = (unsigned)tmp[2] | ((unsigned)tmp[3] << 16);
  o.z = (unsigned)tmp[4] | ((unsigned)tmp[5] << 16);
  o.w = (unsigned)tmp[6] | ((unsigned)tmp[7] << 16);
  reinterpret_cast<uint4*>(dst)[id] = o;
}

__global__ void pack_bias(const float* __restrict__ bq, const float* __restrict__ bk,
                          const float* __restrict__ bv, float kscale, int O,
                          float* __restrict__ out) {
  int i = blockIdx.x * blockDim.x + threadIdx.x;
  if (i >= 6 * O) return;
  int mat = i / O, c = i % O;
  float v = 0.f;
  if (mat == 0) v = bq[c];
  else if (mat == 1) v = bk[c] * kscale;
  else if (mat == 2) v = bv[c];
  out[i] = v;
}

// ---------------- counting sort by dst ----------------
__global__ void hist3(const int* __restrict__ e0, const int* __restrict__ e1,
                      const int* __restrict__ e2, int E, int* __restrict__ hist, int NP) {
  int i = blockIdx.x * blockDim.x + threadIdx.x;
  if (i >= E) return;
  atomicAdd(&hist[0 * NP + e0[E + i]], 1);
  atomicAdd(&hist[1 * NP + e1[E + i]], 1);
  atomicAdd(&hist[2 * NP + e2[E + i]], 1);
}

__device__ __forceinline__ int block_scan_excl256(int v, int* buf, int t, int* total) {
  buf[t] = v;
  __syncthreads();
#pragma unroll
  for (int off = 1; off < 256; off <<= 1) {
    int add = (t >= off) ? buf[t - off] : 0;
    __syncthreads();
    buf[t] += add;
    __syncthreads();
  }
  int incl = buf[t];
  *total = buf[255];
  __syncthreads();
  return incl - v;
}

__global__ void scan_pass1(const int* __restrict__ hist, int* __restrict__ excl,
                           int* __restrict__ bsum, int n, int NP) {
  __shared__ int buf[256];
  int y = blockIdx.y, t = threadIdx.x;
  int i = blockIdx.x * 256 + t;
  int v = (i < n) ? hist[y * NP + i] : 0;
  int total;
  int ex = block_scan_excl256(v, buf, t, &total);
  if (i < NP) excl[y * NP + i] = ex;
  if (t == 0) bsum[y * 256 + blockIdx.x] = total;
}

__global__ void scan_pass2(int* __restrict__ bsum, int nblk) {
  __shared__ int buf[256];
  int y = blockIdx.y, t = threadIdx.x;
  int v = (t < nblk) ? bsum[y * 256 + t] : 0;
  int total;
  int ex = block_scan_excl256(v, buf, t, &total);
  bsum[y * 256 + t] = ex;
}

__global__ void scan_pass3(const int* __restrict__ excl, const int* __restrict__ bsum,
                           int* __restrict__ rowptr, int n, int NP, int RP, int E) {
  int y = blockIdx.y;
  int i = blockIdx.x * 256 + threadIdx.x;
  if (i < n) rowptr[y * RP + i] = excl[y * NP + i] + bsum[y * 256 + blockIdx.x];
  if (i == 0) rowptr[y * RP + n] = E;
}

// scatter into paired int2 (src,dst) -> one 8B store per edge
__global__ void scatter3(const int* __restrict__ e0, const int* __restrict__ e1,
                         const int* __restrict__ e2, int E, const int* __restrict__ rowptr,
                         int* __restrict__ hist, int2* __restrict__ pairs, int NP, int RP) {
  int y = blockIdx.y;
  const int* e = (y == 0) ? e0 : (y == 1) ? e1 : e2;
  int i = blockIdx.x * 256 + threadIdx.x;
  if (i >= E) return;
  int sN = e[i], d = e[E + i];
  int old = atomicSub(&hist[y * NP + d], 1);
  int pos = rowptr[y * RP + d] + old - 1;
  pairs[(size_t)y * E + pos] = make_int2(sN, d);
}

// ---------------- node-level GEMM (as R5) ----------------
template <int IN, int O>
__global__ __launch_bounds__(256, 4) void node_gemm(
    const unsigned short* __restrict__ xb, int N,
    const unsigned short* __restrict__ wpack, const float* __restrict__ bias6,
    unsigned short* __restrict__ Y1, unsigned short* __restrict__ Y2) {
  constexpr int KC = IN / 32;
  constexpr int NCH = O / 16;
  constexpr int CHR = IN / 8;
  constexpr int CM = CHR - 1;
  __shared__ unsigned short tiles[64 * IN];

  const int t = threadIdx.x, w = t >> 6, ln = t & 63;
  const int n0 = blockIdx.x * 64;

  {
    constexpr int RPI = 64 / CHR;
    constexpr int NI = 16 / RPI;
    const int r_in = ln / CHR, c = ln % CHR;
#pragma unroll
    for (int i = 0; i < NI; ++i) {
      int row = w * 16 + i * RPI + r_in;
      int node = min(n0 + row, N - 1);
      int sc = c ^ (row & CM);
      const unsigned short* g = xb + (size_t)node * IN + sc * 8;
      unsigned short* l = &tiles[(size_t)(w * 16 + i * RPI) * IN];
      __builtin_amdgcn_global_load_lds(
          (const __attribute__((address_space(1))) unsigned int*)g,
          (__attribute__((address_space(3))) unsigned int*)l, 16, 0, 0);
    }
  }
  __syncthreads();

  const int col = ln & 15, quad = ln >> 4;
  const int g0 = blockIdx.y * 8 + w * 2;

  f32x4 acc[2][4];
#pragma unroll
  for (int cc = 0; cc < 2; ++cc)
#pragma unroll
    for (int m = 0; m < 4; ++m) acc[cc][m] = (f32x4){0.f, 0.f, 0.f, 0.f};

#pragma unroll
  for (int kc = 0; kc < KC; ++kc) {
    bf16x8 a[4];
#pragma unroll
    for (int m = 0; m < 4; ++m) {
      int row = m * 16 + col;
      int sc = (kc * 4 + quad) ^ (row & CM);
      a[m] = *reinterpret_cast<const bf16x8*>(&tiles[(size_t)row * IN + sc * 8]);
    }
#pragma unroll
    for (int cc = 0; cc < 2; ++cc) {
      const bf16x8 b = *reinterpret_cast<const bf16x8*>(
          wpack + ((size_t)((g0 + cc) * KC + kc) * 64 + ln) * 8);
#pragma unroll
      for (int m = 0; m < 4; ++m)
        acc[cc][m] = __builtin_amdgcn_mfma_f32_16x16x32_bf16(a[m], b, acc[cc][m], 0, 0, 0);
    }
  }

#pragma unroll
  for (int cc = 0; cc < 2; ++cc) {
    int gch = g0 + cc;
    int mat = gch / NCH, ncg = gch % NCH;
    unsigned short* Yp = (mat < 3) ? Y1 : Y2;
    int mo = (mat < 3) ? mat : mat - 3;
    float bv = bias6[gch * 16 + col];
    size_t coloff = (size_t)mo * O + ncg * 16 + col;
#pragma unroll
    for (int m = 0; m < 4; ++m)
#pragma unroll
      for (int r = 0; r < 4; ++r) {
        int node = n0 + m * 16 + quad * 4 + r;
        if (node < N) Yp[(size_t)node * (3 * O) + coloff] = f2bf(acc[cc][m][r] + bv);
      }
  }
}

// ---------------- register-resident edge kernel ----------------
// 256 threads = 32 runs x 8 heads; run = 8 consecutive dst-sorted edges.
// Thread walks its run for its head: q=Y1q[dst]+Y2q[src] etc, thread-local
// softmax, ctx accumulated in HS registers, atomic flush at dst boundaries.
// No LDS, no barriers. Pair indices broadcast within 8-lane groups via shfl.
template <int O, int HS>
__global__ __launch_bounds__(256, 4) void edge_attn_reg(
    const unsigned short* __restrict__ Y1, const unsigned short* __restrict__ Y2,
    const int2* __restrict__ pairs, const int E, float* __restrict__ s) {
  constexpr int NL = HS / 8;  // bf16x8 loads per q/k/v slice
  static_assert(O / HS == 8, "8 heads expected");

  const int t = threadIdx.x;
  const int head = t & 7;
  const int run = t >> 3;
  const int ln = t & 63;
  const int gb = ln & ~7;            // 8-lane group base within wave
  const int base = blockIdx.x * 256 + run * 8;

  int2 myp = pairs[min(base + head, E - 1)];

  float acc[HS];
#pragma unroll
  for (int c = 0; c < HS; ++c) acc[c] = 0.f;

#pragma unroll
  for (int i = 0; i < 8; ++i) {
    const int sN = __shfl(myp.x, gb + i, 64);
    const int dN = __shfl(myp.y, gb + i, 64);
    const int dNext = __shfl(myp.y, gb + ((i + 1) & 7), 64);
    const bool ok = (base + i) < E;
    const float dd = fabsf((float)(dN - sN));
    const float ew = (dd > 8.f) ? 1.f : ((dd == 8.f) ? 0.f : -1.f);

    const unsigned short* b1 = Y1 + (size_t)dN * (3 * O) + head * HS;
    const unsigned short* b2 = Y2 + (size_t)sN * (3 * O) + head * HS;

    float ex[HS];
    float sum = 0.f;
#pragma unroll
    for (int l = 0; l < NL; ++l) {
      bf16x8 q1 = *reinterpret_cast<const bf16x8*>(b1 + l * 8);
      bf16x8 q2 = *reinterpret_cast<const bf16x8*>(b2 + l * 8);
      bf16x8 k1 = *reinterpret_cast<const bf16x8*>(b1 + O + l * 8);
      bf16x8 k2 = *reinterpret_cast<const bf16x8*>(b2 + O + l * 8);
#pragma unroll
      for (int j = 0; j < 8; ++j) {
        float q = b2f(q1[j]) + b2f(q2[j]);
        float k = b2f(k1[j]) + b2f(k2[j]);
        float eo = __expf(q * k);  // k-scale folded into k
        ex[l * 8 + j] = eo;
        sum += eo;
      }
    }
    const float rs = ok ? (ew / sum) : 0.f;
#pragma unroll
    for (int l = 0; l < NL; ++l) {
      bf16x8 v1 = *reinterpret_cast<const bf16x8*>(b1 + 2 * O + l * 8);
      bf16x8 v2 = *reinterpret_cast<const bf16x8*>(b2 + 2 * O + l * 8);
#pragma unroll
      for (int j = 0; j < 8; ++j)
        acc[l * 8 + j] += ex[l * 8 + j] * rs * (b2f(v1[j]) + b2f(v2[j]));
    }
    const bool bound = (i == 7) || (dNext != dN);
    if (bound) {
      float* sp = s + (size_t)dN * O + head * HS;
#pragma unroll
      for (int c = 0; c < HS; ++c) {
        atomicAdd(sp + c, acc[c]);
        acc[c] = 0.f;
      }
    }
  }
}

// ---------------- conversions / finalize ----------------
__global__ void f32_to_bf16(const float* __restrict__ in, unsigned short* __restrict__ out,
                            int n8) {
  int i = blockIdx.x * blockDim.x + threadIdx.x;
  if (i >= n8) return;
  float4 a = reinterpret_cast<const float4*>(in)[2 * i];
  float4 b = reinterpret_cast<const float4*>(in)[2 * i + 1];
  uint4 o;
  o.x = (unsigned)f2bf(a.x) | ((unsigned)f2bf(a.y) << 16);
  o.y = (unsigned)f2bf(a.z) | ((unsigned)f2bf(a.w) << 16);
  o.z = (unsigned)f2bf(b.x) | ((unsigned)f2bf(b.y) << 16);
  o.w = (unsigned)f2bf(b.z) | ((unsigned)f2bf(b.w) << 16);
  reinterpret_cast<uint4*>(out)[i] = o;
}

__global__ void finalize_relu_f32bf16(float* __restrict__ s, const int* __restrict__ rowptr,
                                      unsigned short* __restrict__ xbo, int total4, int Odiv4) {
  int i = blockIdx.x * blockDim.x + threadIdx.x;
  if (i >= total4) return;
  int node = i / Odiv4;
  float c = fmaxf((float)(rowptr[node + 1] - rowptr[node]), 1.0f);
  float4 v = reinterpret_cast<float4*>(s)[i];
  v.x = fmaxf(v.x / c, 0.f);
  v.y = fmaxf(v.y / c, 0.f);
  v.z = fmaxf(v.z / c, 0.f);
  v.w = fmaxf(v.w / c, 0.f);
  reinterpret_cast<float4*>(s)[i] = v;
  ushort4 o = make_ushort4(f2bf(v.x), f2bf(v.y), f2bf(v.z), f2bf(v.w));
  reinterpret_cast<ushort4*>(xbo)[i] = o;
}

__global__ void finalize_relu_bf16(const float* __restrict__ s, const int* __restrict__ rowptr,
                                   unsigned short* __restrict__ xbo, int total4, int Odiv4) {
  int i = blockIdx.x * blockDim.x + threadIdx.x;
  if (i >= total4) return;
  int node = i / Odiv4;
  float c = fmaxf((float)(rowptr[node + 1] - rowptr[node]), 1.0f);
  float4 v = reinterpret_cast<const float4*>(s)[i];
  ushort4 o = make_ushort4(f2bf(fmaxf(v.x / c, 0.f)), f2bf(fmaxf(v.y / c, 0.f)),
                           f2bf(fmaxf(v.z / c, 0.f)), f2bf(fmaxf(v.w / c, 0.f)));
  reinterpret_cast<ushort4*>(xbo)[i] = o;
}

__global__ void finalize_add_relu(float* __restrict__ out, const float* __restrict__ x0,
                                  const int* __restrict__ rowptr, int total4, int Odiv4) {
  int i = blockIdx.x * blockDim.x + threadIdx.x;
  if (i >= total4) return;
  int node = i / Odiv4;
  float c = fmaxf((float)(rowptr[node + 1] - rowptr[node]), 1.0f);
  float4 v = reinterpret_cast<float4*>(out)[i];
  float4 r = reinterpret_cast<const float4*>(x0)[i];
  v.x = fmaxf(v.x / c + r.x, 0.f);
  v.y = fmaxf(v.y / c + r.y, 0.f);
  v.z = fmaxf(v.z / c + r.z, 0.f);
  v.w = fmaxf(v.w / c + r.w, 0.f);
  reinterpret_cast<float4*>(out)[i] = v;
}

extern "C" void kernel_launch(void* const* d_in, const int* in_sizes, int n_in,
                              void* d_out, int out_size, void* d_ws, size_t ws_size,
                              hipStream_t stream) {
  const float* x = (const float*)d_in[0];
  const int* e0 = (const int*)d_in[1];
  const int* e1 = (const int*)d_in[2];
  const int* e2 = (const int*)d_in[3];
  const float* wq0 = (const float*)d_in[5];
  const float* bq0 = (const float*)d_in[6];
  const float* wk0 = (const float*)d_in[7];
  const float* bk0 = (const float*)d_in[8];
  const float* wv0 = (const float*)d_in[9];
  const float* bv0 = (const float*)d_in[10];
  const float* wq1 = (const float*)d_in[11];
  const float* bq1 = (const float*)d_in[12];
  const float* wk1 = (const float*)d_in[13];
  const float* bk1 = (const float*)d_in[14];
  const float* wv1 = (const float*)d_in[15];
  const float* bv1 = (const float*)d_in[16];
  const float* wq2 = (const float*)d_in[17];
  const float* bq2 = (const float*)d_in[18];
  const float* wk2 = (const float*)d_in[19];
  const float* bk2 = (const float*)d_in[20];
  const float* wv2 = (const float*)d_in[21];
  const float* bv2 = (const float*)d_in[22];

  const int N = in_sizes[0] / 128;  // 50000
  const int E = in_sizes[1] / 2;    // 500000
  const int NBLK = (N + 255) / 256;
  const int NP = NBLK * 256;
  const int RP = NP + 256;
  const float SC16 = 0.25f;
  const float SC8 = 0.35355339059327373f;

  // ---- workspace carve-up ----
  unsigned short* wp0 = (unsigned short*)d_ws;       // 98304 shorts
  unsigned short* wp1 = wp0 + 98304;                 // 49152
  unsigned short* wp2 = wp1 + 49152;                 // 49152
  float* bias0 = (float*)(wp2 + 49152);              // 768
  float* bias1 = bias0 + 768;                        // 384
  float* bias2 = bias1 + 384;                        // 768
  unsigned short* xb = (unsigned short*)(bias2 + 768);  // N*128
  unsigned short* Y1 = xb + (size_t)N * 128;         // N*384
  unsigned short* Y2 = Y1 + (size_t)N * 384;         // N*384
  float* s0 = (float*)(Y2 + (size_t)N * 384);        // N*128
  float* s1 = s0 + (size_t)N * 128;                  // N*64
  int* hist = (int*)(s1 + (size_t)N * 64);           // 3*NP
  int* excl = hist + 3 * (size_t)NP;                 // 3*NP
  int* bsum = excl + 3 * (size_t)NP;                 // 768
  int* rowptr = bsum + 768;                          // 3*RP
  int2* pairs = (int2*)(rowptr + 3 * (size_t)RP);    // 3*E int2

  hipMemsetAsync(hist, 0, 3 * (size_t)NP * sizeof(int), stream);
  hipMemsetAsync(s0, 0, (size_t)N * 192 * sizeof(float), stream);
  hipMemsetAsync(d_out, 0, (size_t)out_size * sizeof(float), stream);

  pack_weights6<<<48, 256, 0, stream>>>(wq0, wk0, wv0, wp0, 128, 128, SC16);
  pack_weights6<<<24, 256, 0, stream>>>(wq1, wk1, wv1, wp1, 128, 64, SC8);
  pack_weights6<<<24, 256, 0, stream>>>(wq2, wk2, wv2, wp2, 64, 128, SC16);
  pack_bias<<<3, 256, 0, stream>>>(bq0, bk0, bv0, SC16, 128, bias0);
  pack_bias<<<2, 256, 0, stream>>>(bq1, bk1, bv1, SC8, 64, bias1);
  pack_bias<<<3, 256, 0, stream>>>(bq2, bk2, bv2, SC16, 128, bias2);
  f32_to_bf16<<<(N * 16 + 255) / 256, 256, 0, stream>>>(x, xb, N * 16);

  const int EB256 = (E + 255) / 256;
  hist3<<<EB256, 256, 0, stream>>>(e0, e1, e2, E, hist, NP);
  scan_pass1<<<dim3(NBLK, 3), 256, 0, stream>>>(hist, excl, bsum, N, NP);
  scan_pass2<<<dim3(1, 3), 256, 0, stream>>>(bsum, NBLK);
  scan_pass3<<<dim3(NBLK, 3), 256, 0, stream>>>(excl, bsum, rowptr, N, NP, RP, E);
  scatter3<<<dim3(EB256, 3), 256, 0, stream>>>(e0, e1, e2, E, rowptr, hist, pairs, NP, RP);

  const int NT = (N + 63) / 64;

  // Layer 0: IN=128, O=128, HS=16
  node_gemm<128, 128><<<dim3(NT, 6), 256, 0, stream>>>(xb, N, wp0, bias0, Y1, Y2);
  edge_attn_reg<128, 16><<<EB256, 256, 0, stream>>>(Y1, Y2, pairs, E, s0);
  finalize_relu_f32bf16<<<(N * 32 + 255) / 256, 256, 0, stream>>>(s0, rowptr, xb, N * 32, 32);
  // Layer 1: IN=128, O=64, HS=8
  node_gemm<128, 64><<<dim3(NT, 3), 256, 0, stream>>>(xb, N, wp1, bias1, Y1, Y2);
  edge_attn_reg<64, 8><<<EB256, 256, 0, stream>>>(Y1, Y2, pairs + E, E, s1);
  finalize_relu_bf16<<<(N * 16 + 255) / 256, 256, 0, stream>>>(s1, rowptr + RP, xb, N * 16, 16);
  // Layer 2: IN=64, O=128, HS=16 -> accumulate into d_out
  node_gemm<64, 128><<<dim3(NT, 6), 256, 0, stream>>>(xb, N, wp2, bias2, Y1, Y2);
  edge_attn_reg<128, 16><<<EB256, 256, 0, stream>>>(Y1, Y2, pairs + 2 * (size_t)E, E, (float*)d_out);
  finalize_add_relu<<<(N * 32 + 255) / 256, 256, 0, stream>>>((float*)d_out, s0, rowptr + 2 * RP,
                                                              N * 32, 32);
}

// Round 7
// 633.211 us; speedup vs baseline: 3.7522x; 3.7522x over previous
//
#include <hip/hip_runtime.h>

// EdgeConvEncoder R7: R5 edge-kernel structure restored (thread = one
// (edge, head), all loads up-front -> max MLP; LDS ctx + segmented reduction)
// + R6's paired int2 scatter (half the scattered cachelines).
// R6's register-run walk removed: it serialized 16 dependent cache-miss
// round-trips per thread (VALUBusy 3%) -- MLP beats register residency here.

typedef short bf16x8 __attribute__((ext_vector_type(8)));
typedef float f32x4 __attribute__((ext_vector_type(4)));

__device__ __forceinline__ unsigned short f2bf(float f) {
  unsigned int u = __float_as_uint(f);
  u += 0x7FFFu + ((u >> 16) & 1u);  // round-to-nearest-even
  return (unsigned short)(u >> 16);
}
__device__ __forceinline__ float b2f(short s) {
  return __uint_as_float(((unsigned)(unsigned short)s) << 16);
}

// ---------------- weight packing: 6 matrices (W1=top-bot x3, W2=bot x3) ----
__global__ void pack_weights6(const float* __restrict__ wq, const float* __restrict__ wk,
                              const float* __restrict__ wv, unsigned short* __restrict__ dst,
                              int IN, int O, float kscale) {
  int id = blockIdx.x * blockDim.x + threadIdx.x;
  int kchunks = IN >> 5, nchunks = O >> 4;
  int total = 6 * nchunks * kchunks * 64;
  if (id >= total) return;
  int lane = id & 63;
  int frag = id >> 6;
  int kc = frag % kchunks;
  int nc = (frag / kchunks) % nchunks;
  int mat = frag / (kchunks * nchunks);
  const float* w = (mat % 3 == 0) ? wq : (mat % 3 == 1) ? wk : wv;
  float mul = (mat % 3 == 1) ? kscale : 1.0f;
  int n = nc * 16 + (lane & 15);
  int k0 = kc * 32 + (lane >> 4) * 8;
  unsigned short tmp[8];
#pragma unroll
  for (int j = 0; j < 8; ++j) {
    int row = k0 + j;
    float bot = w[(size_t)(IN + row) * O + n];
    float val = (mat < 3) ? (w[(size_t)row * O + n] - bot) : bot;
    tmp[j] = f2bf(val * mul);
  }
  uint4 o;
  o.x = (unsigned)tmp[0] | ((unsigned)tmp[1] << 16);
  o.y = (unsigned)tmp[2] | ((unsigned)tmp[3] << 16);
  o.z = (unsigned)tmp[4] | ((unsigned)tmp[5] << 16);
  o.w = (unsigned)tmp[6] | ((unsigned)tmp[7] << 16);
  reinterpret_cast<uint4*>(dst)[id] = o;
}

__global__ void pack_bias(const float* __restrict__ bq, const float* __restrict__ bk,
                          const float* __restrict__ bv, float kscale, int O,
                          float* __restrict__ out) {
  int i = blockIdx.x * blockDim.x + threadIdx.x;
  if (i >= 6 * O) return;
  int mat = i / O, c = i % O;
  float v = 0.f;
  if (mat == 0) v = bq[c];
  else if (mat == 1) v = bk[c] * kscale;
  else if (mat == 2) v = bv[c];
  out[i] = v;
}

// ---------------- counting sort by dst ----------------
__global__ void hist3(const int* __restrict__ e0, const int* __restrict__ e1,
                      const int* __restrict__ e2, int E, int* __restrict__ hist, int NP) {
  int i = blockIdx.x * blockDim.x + threadIdx.x;
  if (i >= E) return;
  atomicAdd(&hist[0 * NP + e0[E + i]], 1);
  atomicAdd(&hist[1 * NP + e1[E + i]], 1);
  atomicAdd(&hist[2 * NP + e2[E + i]], 1);
}

__device__ __forceinline__ int block_scan_excl256(int v, int* buf, int t, int* total) {
  buf[t] = v;
  __syncthreads();
#pragma unroll
  for (int off = 1; off < 256; off <<= 1) {
    int add = (t >= off) ? buf[t - off] : 0;
    __syncthreads();
    buf[t] += add;
    __syncthreads();
  }
  int incl = buf[t];
  *total = buf[255];
  __syncthreads();
  return incl - v;
}

__global__ void scan_pass1(const int* __restrict__ hist, int* __restrict__ excl,
                           int* __restrict__ bsum, int n, int NP) {
  __shared__ int buf[256];
  int y = blockIdx.y, t = threadIdx.x;
  int i = blockIdx.x * 256 + t;
  int v = (i < n) ? hist[y * NP + i] : 0;
  int total;
  int ex = block_scan_excl256(v, buf, t, &total);
  if (i < NP) excl[y * NP + i] = ex;
  if (t == 0) bsum[y * 256 + blockIdx.x] = total;
}

__global__ void scan_pass2(int* __restrict__ bsum, int nblk) {
  __shared__ int buf[256];
  int y = blockIdx.y, t = threadIdx.x;
  int v = (t < nblk) ? bsum[y * 256 + t] : 0;
  int total;
  int ex = block_scan_excl256(v, buf, t, &total);
  bsum[y * 256 + t] = ex;
}

__global__ void scan_pass3(const int* __restrict__ excl, const int* __restrict__ bsum,
                           int* __restrict__ rowptr, int n, int NP, int RP, int E) {
  int y = blockIdx.y;
  int i = blockIdx.x * 256 + threadIdx.x;
  if (i < n) rowptr[y * RP + i] = excl[y * NP + i] + bsum[y * 256 + blockIdx.x];
  if (i == 0) rowptr[y * RP + n] = E;
}

// scatter into paired int2 (src,dst) -> one 8B store per edge
__global__ void scatter3(const int* __restrict__ e0, const int* __restrict__ e1,
                         const int* __restrict__ e2, int E, const int* __restrict__ rowptr,
                         int* __restrict__ hist, int2* __restrict__ pairs, int NP, int RP) {
  int y = blockIdx.y;
  const int* e = (y == 0) ? e0 : (y == 1) ? e1 : e2;
  int i = blockIdx.x * 256 + threadIdx.x;
  if (i >= E) return;
  int sN = e[i], d = e[E + i];
  int old = atomicSub(&hist[y * NP + d], 1);
  int pos = rowptr[y * RP + d] + old - 1;
  pairs[(size_t)y * E + pos] = make_int2(sN, d);
}

// ---------------- node-level GEMM ----------------
template <int IN, int O>
__global__ __launch_bounds__(256, 4) void node_gemm(
    const unsigned short* __restrict__ xb, int N,
    const unsigned short* __restrict__ wpack, const float* __restrict__ bias6,
    unsigned short* __restrict__ Y1, unsigned short* __restrict__ Y2) {
  constexpr int KC = IN / 32;
  constexpr int NCH = O / 16;
  constexpr int CHR = IN / 8;
  constexpr int CM = CHR - 1;
  __shared__ unsigned short tiles[64 * IN];

  const int t = threadIdx.x, w = t >> 6, ln = t & 63;
  const int n0 = blockIdx.x * 64;

  {
    constexpr int RPI = 64 / CHR;
    constexpr int NI = 16 / RPI;
    const int r_in = ln / CHR, c = ln % CHR;
#pragma unroll
    for (int i = 0; i < NI; ++i) {
      int row = w * 16 + i * RPI + r_in;
      int node = min(n0 + row, N - 1);
      int sc = c ^ (row & CM);
      const unsigned short* g = xb + (size_t)node * IN + sc * 8;
      unsigned short* l = &tiles[(size_t)(w * 16 + i * RPI) * IN];
      __builtin_amdgcn_global_load_lds(
          (const __attribute__((address_space(1))) unsigned int*)g,
          (__attribute__((address_space(3))) unsigned int*)l, 16, 0, 0);
    }
  }
  __syncthreads();

  const int col = ln & 15, quad = ln >> 4;
  const int g0 = blockIdx.y * 8 + w * 2;

  f32x4 acc[2][4];
#pragma unroll
  for (int cc = 0; cc < 2; ++cc)
#pragma unroll
    for (int m = 0; m < 4; ++m) acc[cc][m] = (f32x4){0.f, 0.f, 0.f, 0.f};

#pragma unroll
  for (int kc = 0; kc < KC; ++kc) {
    bf16x8 a[4];
#pragma unroll
    for (int m = 0; m < 4; ++m) {
      int row = m * 16 + col;
      int sc = (kc * 4 + quad) ^ (row & CM);
      a[m] = *reinterpret_cast<const bf16x8*>(&tiles[(size_t)row * IN + sc * 8]);
    }
#pragma unroll
    for (int cc = 0; cc < 2; ++cc) {
      const bf16x8 b = *reinterpret_cast<const bf16x8*>(
          wpack + ((size_t)((g0 + cc) * KC + kc) * 64 + ln) * 8);
#pragma unroll
      for (int m = 0; m < 4; ++m)
        acc[cc][m] = __builtin_amdgcn_mfma_f32_16x16x32_bf16(a[m], b, acc[cc][m], 0, 0, 0);
    }
  }

#pragma unroll
  for (int cc = 0; cc < 2; ++cc) {
    int gch = g0 + cc;
    int mat = gch / NCH, ncg = gch % NCH;
    unsigned short* Yp = (mat < 3) ? Y1 : Y2;
    int mo = (mat < 3) ? mat : mat - 3;
    float bv = bias6[gch * 16 + col];
    size_t coloff = (size_t)mo * O + ncg * 16 + col;
#pragma unroll
    for (int m = 0; m < 4; ++m)
#pragma unroll
      for (int r = 0; r < 4; ++r) {
        int node = n0 + m * 16 + quad * 4 + r;
        if (node < N) Yp[(size_t)node * (3 * O) + coloff] = f2bf(acc[cc][m][r] + bv);
      }
  }
}

// ---------------- gather-based edge kernel (R5 structure) ----------------
// 512 threads, 64 edges, 8 threads/edge, thread = one head (HS channels).
// All 6 Y-vectors loaded up-front (one vmcnt batch). Thread-local softmax.
// ctx -> LDS chunk-rotated, then segmented reduction -> atomics.
template <int O, int HS>
__global__ __launch_bounds__(512, 6) void edge_attn_kernel(
    const unsigned short* __restrict__ Y1, const unsigned short* __restrict__ Y2,
    const int2* __restrict__ pairs, const int E, float* __restrict__ s) {
  constexpr int NL = HS / 8;     // bf16x8 loads per matrix
  constexpr int PM = O / 4 - 1;  // LDS chunk mask
  __shared__ float ctx[64 * O];
  __shared__ int dstL[64];

  const int t = threadIdx.x;
  const int e = t >> 3, head = t & 7;
  const int eG = blockIdx.x * 64 + e;
  const int eC = min(eG, E - 1);
  const bool valid = eG < E;
  const int2 p = pairs[eC];
  const int sN = p.x, dN = p.y;
  if ((t & 7) == 0) dstL[e] = dN;
  const float dd = fabsf((float)(dN - sN));
  const float ew = (dd > 8.f) ? 1.f : ((dd == 8.f) ? 0.f : -1.f);

  const unsigned short* b1 = Y1 + (size_t)dN * (3 * O) + head * HS;
  const unsigned short* b2 = Y2 + (size_t)sN * (3 * O) + head * HS;

  // hoist ALL loads (q,k,v from both tables) -> one vmcnt batch
  bf16x8 q1[NL], q2[NL], k1[NL], k2[NL], v1[NL], v2[NL];
#pragma unroll
  for (int l = 0; l < NL; ++l) {
    q1[l] = *reinterpret_cast<const bf16x8*>(b1 + l * 8);
    q2[l] = *reinterpret_cast<const bf16x8*>(b2 + l * 8);
    k1[l] = *reinterpret_cast<const bf16x8*>(b1 + O + l * 8);
    k2[l] = *reinterpret_cast<const bf16x8*>(b2 + O + l * 8);
    v1[l] = *reinterpret_cast<const bf16x8*>(b1 + 2 * O + l * 8);
    v2[l] = *reinterpret_cast<const bf16x8*>(b2 + 2 * O + l * 8);
  }

  float ex[HS];
  float sum = 0.f;
#pragma unroll
  for (int l = 0; l < NL; ++l)
#pragma unroll
    for (int j = 0; j < 8; ++j) {
      float q = b2f(q1[l][j]) + b2f(q2[l][j]);
      float k = b2f(k1[l][j]) + b2f(k2[l][j]);
      float eo = __expf(q * k);  // k-scale folded into k
      ex[l * 8 + j] = eo;
      sum += eo;
    }
  const float rs = valid ? (ew / sum) : 0.f;
#pragma unroll
  for (int l = 0; l < NL; ++l) {
#pragma unroll
    for (int g2 = 0; g2 < 2; ++g2) {
      f32x4 o;
#pragma unroll
      for (int j2 = 0; j2 < 4; ++j2) {
        int j = g2 * 4 + j2;
        o[j2] = ex[l * 8 + j] * rs * (b2f(v1[l][j]) + b2f(v2[l][j]));
      }
      int g = l * 2 + g2;               // chunk-in-head
      int pch = (g * 8 + head + e) & PM;  // rotated chunk position
      *reinterpret_cast<f32x4*>(&ctx[e * O + pch * 4]) = o;
    }
  }
  __syncthreads();

  // segred: col = head*HS + c (bit-spread so a wave covers all heads)
  {
    constexpr int GRP = 512 / O;
    constexpr int EPT = 64 / GRP;
    const int hs2 = t & 7;
    const int cs = (t >> 3) & (HS - 1);
    const int colA = hs2 * HS + cs;
    const int seg0 = (t / O) * EPT;
    const int inv = (cs >> 2) * 8 + hs2;
    const int js = cs & 3;
    float run = 0.f;
#pragma unroll
    for (int i = 0; i < EPT; ++i) {
      int ee = seg0 + i;
      int pch = (inv + ee) & PM;
      run += ctx[ee * O + pch * 4 + js];
      bool bound = (i == EPT - 1) || (dstL[ee + 1] != dstL[ee]);
      if (bound) {
        atomicAdd(&s[(size_t)dstL[ee] * O + colA], run);
        run = 0.f;
      }
    }
  }
}

// ---------------- conversions / finalize ----------------
__global__ void f32_to_bf16(const float* __restrict__ in, unsigned short* __restrict__ out,
                            int n8) {
  int i = blockIdx.x * blockDim.x + threadIdx.x;
  if (i >= n8) return;
  float4 a = reinterpret_cast<const float4*>(in)[2 * i];
  float4 b = reinterpret_cast<const float4*>(in)[2 * i + 1];
  uint4 o;
  o.x = (unsigned)f2bf(a.x) | ((unsigned)f2bf(a.y) << 16);
  o.y = (unsigned)f2bf(a.z) | ((unsigned)f2bf(a.w) << 16);
  o.z = (unsigned)f2bf(b.x) | ((unsigned)f2bf(b.y) << 16);
  o.w = (unsigned)f2bf(b.z) | ((unsigned)f2bf(b.w) << 16);
  reinterpret_cast<uint4*>(out)[i] = o;
}

__global__ void finalize_relu_f32bf16(float* __restrict__ s, const int* __restrict__ rowptr,
                                      unsigned short* __restrict__ xbo, int total4, int Odiv4) {
  int i = blockIdx.x * blockDim.x + threadIdx.x;
  if (i >= total4) return;
  int node = i / Odiv4;
  float c = fmaxf((float)(rowptr[node + 1] - rowptr[node]), 1.0f);
  float4 v = reinterpret_cast<float4*>(s)[i];
  v.x = fmaxf(v.x / c, 0.f);
  v.y = fmaxf(v.y / c, 0.f);
  v.z = fmaxf(v.z / c, 0.f);
  v.w = fmaxf(v.w / c, 0.f);
  reinterpret_cast<float4*>(s)[i] = v;
  ushort4 o = make_ushort4(f2bf(v.x), f2bf(v.y), f2bf(v.z), f2bf(v.w));
  reinterpret_cast<ushort4*>(xbo)[i] = o;
}

__global__ void finalize_relu_bf16(const float* __restrict__ s, const int* __restrict__ rowptr,
                                   unsigned short* __restrict__ xbo, int total4, int Odiv4) {
  int i = blockIdx.x * blockDim.x + threadIdx.x;
  if (i >= total4) return;
  int node = i / Odiv4;
  float c = fmaxf((float)(rowptr[node + 1] - rowptr[node]), 1.0f);
  float4 v = reinterpret_cast<const float4*>(s)[i];
  ushort4 o = make_ushort4(f2bf(fmaxf(v.x / c, 0.f)), f2bf(fmaxf(v.y / c, 0.f)),
                           f2bf(fmaxf(v.z / c, 0.f)), f2bf(fmaxf(v.w / c, 0.f)));
  reinterpret_cast<ushort4*>(xbo)[i] = o;
}

__global__ void finalize_add_relu(float* __restrict__ out, const float* __restrict__ x0,
                                  const int* __restrict__ rowptr, int total4, int Odiv4) {
  int i = blockIdx.x * blockDim.x + threadIdx.x;
  if (i >= total4) return;
  int node = i / Odiv4;
  float c = fmaxf((float)(rowptr[node + 1] - rowptr[node]), 1.0f);
  float4 v = reinterpret_cast<float4*>(out)[i];
  float4 r = reinterpret_cast<const float4*>(x0)[i];
  v.x = fmaxf(v.x / c + r.x, 0.f);
  v.y = fmaxf(v.y / c + r.y, 0.f);
  v.z = fmaxf(v.z / c + r.z, 0.f);
  v.w = fmaxf(v.w / c + r.w, 0.f);
  reinterpret_cast<float4*>(out)[i] = v;
}

extern "C" void kernel_launch(void* const* d_in, const int* in_sizes, int n_in,
                              void* d_out, int out_size, void* d_ws, size_t ws_size,
                              hipStream_t stream) {
  const float* x = (const float*)d_in[0];
  const int* e0 = (const int*)d_in[1];
  const int* e1 = (const int*)d_in[2];
  const int* e2 = (const int*)d_in[3];
  const float* wq0 = (const float*)d_in[5];
  const float* bq0 = (const float*)d_in[6];
  const float* wk0 = (const float*)d_in[7];
  const float* bk0 = (const float*)d_in[8];
  const float* wv0 = (const float*)d_in[9];
  const float* bv0 = (const float*)d_in[10];
  const float* wq1 = (const float*)d_in[11];
  const float* bq1 = (const float*)d_in[12];
  const float* wk1 = (const float*)d_in[13];
  const float* bk1 = (const float*)d_in[14];
  const float* wv1 = (const float*)d_in[15];
  const float* bv1 = (const float*)d_in[16];
  const float* wq2 = (const float*)d_in[17];
  const float* bq2 = (const float*)d_in[18];
  const float* wk2 = (const float*)d_in[19];
  const float* bk2 = (const float*)d_in[20];
  const float* wv2 = (const float*)d_in[21];
  const float* bv2 = (const float*)d_in[22];

  const int N = in_sizes[0] / 128;  // 50000
  const int E = in_sizes[1] / 2;    // 500000
  const int NBLK = (N + 255) / 256;
  const int NP = NBLK * 256;
  const int RP = NP + 256;
  const float SC16 = 0.25f;
  const float SC8 = 0.35355339059327373f;

  // ---- workspace carve-up ----
  unsigned short* wp0 = (unsigned short*)d_ws;       // 98304 shorts
  unsigned short* wp1 = wp0 + 98304;                 // 49152
  unsigned short* wp2 = wp1 + 49152;                 // 49152
  float* bias0 = (float*)(wp2 + 49152);              // 768
  float* bias1 = bias0 + 768;                        // 384
  float* bias2 = bias1 + 384;                        // 768
  unsigned short* xb = (unsigned short*)(bias2 + 768);  // N*128
  unsigned short* Y1 = xb + (size_t)N * 128;         // N*384
  unsigned short* Y2 = Y1 + (size_t)N * 384;         // N*384
  float* s0 = (float*)(Y2 + (size_t)N * 384);        // N*128
  float* s1 = s0 + (size_t)N * 128;                  // N*64
  int* hist = (int*)(s1 + (size_t)N * 64);           // 3*NP
  int* excl = hist + 3 * (size_t)NP;                 // 3*NP
  int* bsum = excl + 3 * (size_t)NP;                 // 768
  int* rowptr = bsum + 768;                          // 3*RP
  int2* pairs = (int2*)(rowptr + 3 * (size_t)RP);    // 3*E int2

  hipMemsetAsync(hist, 0, 3 * (size_t)NP * sizeof(int), stream);
  hipMemsetAsync(s0, 0, (size_t)N * 192 * sizeof(float), stream);
  hipMemsetAsync(d_out, 0, (size_t)out_size * sizeof(float), stream);

  pack_weights6<<<48, 256, 0, stream>>>(wq0, wk0, wv0, wp0, 128, 128, SC16);
  pack_weights6<<<24, 256, 0, stream>>>(wq1, wk1, wv1, wp1, 128, 64, SC8);
  pack_weights6<<<24, 256, 0, stream>>>(wq2, wk2, wv2, wp2, 64, 128, SC16);
  pack_bias<<<3, 256, 0, stream>>>(bq0, bk0, bv0, SC16, 128, bias0);
  pack_bias<<<2, 256, 0, stream>>>(bq1, bk1, bv1, SC8, 64, bias1);
  pack_bias<<<3, 256, 0, stream>>>(bq2, bk2, bv2, SC16, 128, bias2);
  f32_to_bf16<<<(N * 16 + 255) / 256, 256, 0, stream>>>(x, xb, N * 16);

  const int EB256 = (E + 255) / 256;
  hist3<<<EB256, 256, 0, stream>>>(e0, e1, e2, E, hist, NP);
  scan_pass1<<<dim3(NBLK, 3), 256, 0, stream>>>(hist, excl, bsum, N, NP);
  scan_pass2<<<dim3(1, 3), 256, 0, stream>>>(bsum, NBLK);
  scan_pass3<<<dim3(NBLK, 3), 256, 0, stream>>>(excl, bsum, rowptr, N, NP, RP, E);
  scatter3<<<dim3(EB256, 3), 256, 0, stream>>>(e0, e1, e2, E, rowptr, hist, pairs, NP, RP);

  const int NT = (N + 63) / 64;
  const int EBK = (E + 63) / 64;

  // Layer 0: IN=128, O=128, HS=16
  node_gemm<128, 128><<<dim3(NT, 6), 256, 0, stream>>>(xb, N, wp0, bias0, Y1, Y2);
  edge_attn_kernel<128, 16><<<EBK, 512, 0, stream>>>(Y1, Y2, pairs, E, s0);
  finalize_relu_f32bf16<<<(N * 32 + 255) / 256, 256, 0, stream>>>(s0, rowptr, xb, N * 32, 32);
  // Layer 1: IN=128, O=64, HS=8
  node_gemm<128, 64><<<dim3(NT, 3), 256, 0, stream>>>(xb, N, wp1, bias1, Y1, Y2);
  edge_attn_kernel<64, 8><<<EBK, 512, 0, stream>>>(Y1, Y2, pairs + E, E, s1);
  finalize_relu_bf16<<<(N * 16 + 255) / 256, 256, 0, stream>>>(s1, rowptr + RP, xb, N * 16, 16);
  // Layer 2: IN=64, O=128, HS=16 -> accumulate into d_out
  node_gemm<64, 128><<<dim3(NT, 6), 256, 0, stream>>>(xb, N, wp2, bias2, Y1, Y2);
  edge_attn_kernel<128, 16><<<EBK, 512, 0, stream>>>(Y1, Y2, pairs + 2 * (size_t)E, E, (float*)d_out);
  finalize_add_relu<<<(N * 32 + 255) / 256, 256, 0, stream>>>((float*)d_out, s0, rowptr + 2 * RP,
                                                              N * 32, 32);
}

// Round 8
// 591.630 us; speedup vs baseline: 4.0159x; 1.0703x over previous
//
#include <hip/hip_runtime.h>

// EdgeConvEncoder R8 (on R7):
//  - hist3 captures per-edge rank (sequential 4B writes) -> scatter3 loses
//    its atomicSub pass; pairs written with nontemporal stores (bypass L2
//    write-allocate churn on partial lines)
//  - edge_attn: bijective XCD-contiguous block swizzle -> each XCD's L2
//    caches its own ~4.8MB dst-slice of Y1 (dst gathers L2-resident)

typedef short bf16x8 __attribute__((ext_vector_type(8)));
typedef float f32x4 __attribute__((ext_vector_type(4)));

__device__ __forceinline__ unsigned short f2bf(float f) {
  unsigned int u = __float_as_uint(f);
  u += 0x7FFFu + ((u >> 16) & 1u);  // round-to-nearest-even
  return (unsigned short)(u >> 16);
}
__device__ __forceinline__ float b2f(short s) {
  return __uint_as_float(((unsigned)(unsigned short)s) << 16);
}

// ---------------- weight packing: 6 matrices (W1=top-bot x3, W2=bot x3) ----
__global__ void pack_weights6(const float* __restrict__ wq, const float* __restrict__ wk,
                              const float* __restrict__ wv, unsigned short* __restrict__ dst,
                              int IN, int O, float kscale) {
  int id = blockIdx.x * blockDim.x + threadIdx.x;
  int kchunks = IN >> 5, nchunks = O >> 4;
  int total = 6 * nchunks * kchunks * 64;
  if (id >= total) return;
  int lane = id & 63;
  int frag = id >> 6;
  int kc = frag % kchunks;
  int nc = (frag / kchunks) % nchunks;
  int mat = frag / (kchunks * nchunks);
  const float* w = (mat % 3 == 0) ? wq : (mat % 3 == 1) ? wk : wv;
  float mul = (mat % 3 == 1) ? kscale : 1.0f;
  int n = nc * 16 + (lane & 15);
  int k0 = kc * 32 + (lane >> 4) * 8;
  unsigned short tmp[8];
#pragma unroll
  for (int j = 0; j < 8; ++j) {
    int row = k0 + j;
    float bot = w[(size_t)(IN + row) * O + n];
    float val = (mat < 3) ? (w[(size_t)row * O + n] - bot) : bot;
    tmp[j] = f2bf(val * mul);
  }
  uint4 o;
  o.x = (unsigned)tmp[0] | ((unsigned)tmp[1] << 16);
  o.y = (unsigned)tmp[2] | ((unsigned)tmp[3] << 16);
  o.z = (unsigned)tmp[4] | ((unsigned)tmp[5] << 16);
  o.w = (unsigned)tmp[6] | ((unsigned)tmp[7] << 16);
  reinterpret_cast<uint4*>(dst)[id] = o;
}

__global__ void pack_bias(const float* __restrict__ bq, const float* __restrict__ bk,
                          const float* __restrict__ bv, float kscale, int O,
                          float* __restrict__ out) {
  int i = blockIdx.x * blockDim.x + threadIdx.x;
  if (i >= 6 * O) return;
  int mat = i / O, c = i % O;
  float v = 0.f;
  if (mat == 0) v = bq[c];
  else if (mat == 1) v = bk[c] * kscale;
  else if (mat == 2) v = bv[c];
  out[i] = v;
}

// ---------------- counting sort by dst ----------------
// hist + per-edge rank (rank written sequentially -> cheap)
__global__ void hist3(const int* __restrict__ e0, const int* __restrict__ e1,
                      const int* __restrict__ e2, int E, int* __restrict__ hist,
                      int* __restrict__ rank, int NP) {
  int i = blockIdx.x * blockDim.x + threadIdx.x;
  if (i >= E) return;
  rank[0 * E + i] = atomicAdd(&hist[0 * NP + e0[E + i]], 1);
  rank[1 * E + i] = atomicAdd(&hist[1 * NP + e1[E + i]], 1);
  rank[2 * E + i] = atomicAdd(&hist[2 * NP + e2[E + i]], 1);
}

__device__ __forceinline__ int block_scan_excl256(int v, int* buf, int t, int* total) {
  buf[t] = v;
  __syncthreads();
#pragma unroll
  for (int off = 1; off < 256; off <<= 1) {
    int add = (t >= off) ? buf[t - off] : 0;
    __syncthreads();
    buf[t] += add;
    __syncthreads();
  }
  int incl = buf[t];
  *total = buf[255];
  __syncthreads();
  return incl - v;
}

__global__ void scan_pass1(const int* __restrict__ hist, int* __restrict__ excl,
                           int* __restrict__ bsum, int n, int NP) {
  __shared__ int buf[256];
  int y = blockIdx.y, t = threadIdx.x;
  int i = blockIdx.x * 256 + t;
  int v = (i < n) ? hist[y * NP + i] : 0;
  int total;
  int ex = block_scan_excl256(v, buf, t, &total);
  if (i < NP) excl[y * NP + i] = ex;
  if (t == 0) bsum[y * 256 + blockIdx.x] = total;
}

__global__ void scan_pass2(int* __restrict__ bsum, int nblk) {
  __shared__ int buf[256];
  int y = blockIdx.y, t = threadIdx.x;
  int v = (t < nblk) ? bsum[y * 256 + t] : 0;
  int total;
  int ex = block_scan_excl256(v, buf, t, &total);
  bsum[y * 256 + t] = ex;
}

__global__ void scan_pass3(const int* __restrict__ excl, const int* __restrict__ bsum,
                           int* __restrict__ rowptr, int n, int NP, int RP, int E) {
  int y = blockIdx.y;
  int i = blockIdx.x * 256 + threadIdx.x;
  if (i < n) rowptr[y * RP + i] = excl[y * NP + i] + bsum[y * 256 + blockIdx.x];
  if (i == 0) rowptr[y * RP + n] = E;
}

// scatter: pos = rowptr[d] + rank (no atomics); nontemporal 8B store
__global__ void scatter3(const int* __restrict__ e0, const int* __restrict__ e1,
                         const int* __restrict__ e2, int E, const int* __restrict__ rowptr,
                         const int* __restrict__ rank, long long* __restrict__ pairs,
                         int NP, int RP) {
  int y = blockIdx.y;
  const int* e = (y == 0) ? e0 : (y == 1) ? e1 : e2;
  int i = blockIdx.x * 256 + threadIdx.x;
  if (i >= E) return;
  int sN = e[i], d = e[E + i];
  int pos = rowptr[y * RP + d] + rank[(size_t)y * E + i];
  long long val = ((long long)(unsigned)d << 32) | (unsigned)sN;  // x=sN, y=d
  __builtin_nontemporal_store(val, &pairs[(size_t)y * E + pos]);
}

// ---------------- node-level GEMM ----------------
template <int IN, int O>
__global__ __launch_bounds__(256, 4) void node_gemm(
    const unsigned short* __restrict__ xb, int N,
    const unsigned short* __restrict__ wpack, const float* __restrict__ bias6,
    unsigned short* __restrict__ Y1, unsigned short* __restrict__ Y2) {
  constexpr int KC = IN / 32;
  constexpr int NCH = O / 16;
  constexpr int CHR = IN / 8;
  constexpr int CM = CHR - 1;
  __shared__ unsigned short tiles[64 * IN];

  const int t = threadIdx.x, w = t >> 6, ln = t & 63;
  const int n0 = blockIdx.x * 64;

  {
    constexpr int RPI = 64 / CHR;
    constexpr int NI = 16 / RPI;
    const int r_in = ln / CHR, c = ln % CHR;
#pragma unroll
    for (int i = 0; i < NI; ++i) {
      int row = w * 16 + i * RPI + r_in;
      int node = min(n0 + row, N - 1);
      int sc = c ^ (row & CM);
      const unsigned short* g = xb + (size_t)node * IN + sc * 8;
      unsigned short* l = &tiles[(size_t)(w * 16 + i * RPI) * IN];
      __builtin_amdgcn_global_load_lds(
          (const __attribute__((address_space(1))) unsigned int*)g,
          (__attribute__((address_space(3))) unsigned int*)l, 16, 0, 0);
    }
  }
  __syncthreads();

  const int col = ln & 15, quad = ln >> 4;
  const int g0 = blockIdx.y * 8 + w * 2;

  f32x4 acc[2][4];
#pragma unroll
  for (int cc = 0; cc < 2; ++cc)
#pragma unroll
    for (int m = 0; m < 4; ++m) acc[cc][m] = (f32x4){0.f, 0.f, 0.f, 0.f};

#pragma unroll
  for (int kc = 0; kc < KC; ++kc) {
    bf16x8 a[4];
#pragma unroll
    for (int m = 0; m < 4; ++m) {
      int row = m * 16 + col;
      int sc = (kc * 4 + quad) ^ (row & CM);
      a[m] = *reinterpret_cast<const bf16x8*>(&tiles[(size_t)row * IN + sc * 8]);
    }
#pragma unroll
    for (int cc = 0; cc < 2; ++cc) {
      const bf16x8 b = *reinterpret_cast<const bf16x8*>(
          wpack + ((size_t)((g0 + cc) * KC + kc) * 64 + ln) * 8);
#pragma unroll
      for (int m = 0; m < 4; ++m)
        acc[cc][m] = __builtin_amdgcn_mfma_f32_16x16x32_bf16(a[m], b, acc[cc][m], 0, 0, 0);
    }
  }

#pragma unroll
  for (int cc = 0; cc < 2; ++cc) {
    int gch = g0 + cc;
    int mat = gch / NCH, ncg = gch % NCH;
    unsigned short* Yp = (mat < 3) ? Y1 : Y2;
    int mo = (mat < 3) ? mat : mat - 3;
    float bv = bias6[gch * 16 + col];
    size_t coloff = (size_t)mo * O + ncg * 16 + col;
#pragma unroll
    for (int m = 0; m < 4; ++m)
#pragma unroll
      for (int r = 0; r < 4; ++r) {
        int node = n0 + m * 16 + quad * 4 + r;
        if (node < N) Yp[(size_t)node * (3 * O) + coloff] = f2bf(acc[cc][m][r] + bv);
      }
  }
}

// ---------------- gather-based edge kernel ----------------
// 512 threads, 64 edges, 8 threads/edge, thread = one head (HS channels).
// XCD-contiguous bijective block swizzle: XCD x gets logical chunk x ->
// each XCD's L2 caches its dst-slice of Y1. Grid = 8*ceil(EBK/8).
template <int O, int HS>
__global__ __launch_bounds__(512, 6) void edge_attn_kernel(
    const unsigned short* __restrict__ Y1, const unsigned short* __restrict__ Y2,
    const int2* __restrict__ pairs, const int E, float* __restrict__ s) {
  constexpr int NL = HS / 8;
  constexpr int PM = O / 4 - 1;
  __shared__ float ctx[64 * O];
  __shared__ int dstL[64];

  const int chunkB = gridDim.x >> 3;
  const int lb = (blockIdx.x & 7) * chunkB + (blockIdx.x >> 3);
  if (lb * 64 >= E) return;

  const int t = threadIdx.x;
  const int e = t >> 3, head = t & 7;
  const int eG = lb * 64 + e;
  const int eC = min(eG, E - 1);
  const bool valid = eG < E;
  const int2 p = pairs[eC];
  const int sN = p.x, dN = p.y;
  if ((t & 7) == 0) dstL[e] = dN;
  const float dd = fabsf((float)(dN - sN));
  const float ew = (dd > 8.f) ? 1.f : ((dd == 8.f) ? 0.f : -1.f);

  const unsigned short* b1 = Y1 + (size_t)dN * (3 * O) + head * HS;
  const unsigned short* b2 = Y2 + (size_t)sN * (3 * O) + head * HS;

  bf16x8 q1[NL], q2[NL], k1[NL], k2[NL], v1[NL], v2[NL];
#pragma unroll
  for (int l = 0; l < NL; ++l) {
    q1[l] = *reinterpret_cast<const bf16x8*>(b1 + l * 8);
    q2[l] = *reinterpret_cast<const bf16x8*>(b2 + l * 8);
    k1[l] = *reinterpret_cast<const bf16x8*>(b1 + O + l * 8);
    k2[l] = *reinterpret_cast<const bf16x8*>(b2 + O + l * 8);
    v1[l] = *reinterpret_cast<const bf16x8*>(b1 + 2 * O + l * 8);
    v2[l] = *reinterpret_cast<const bf16x8*>(b2 + 2 * O + l * 8);
  }

  float ex[HS];
  float sum = 0.f;
#pragma unroll
  for (int l = 0; l < NL; ++l)
#pragma unroll
    for (int j = 0; j < 8; ++j) {
      float q = b2f(q1[l][j]) + b2f(q2[l][j]);
      float k = b2f(k1[l][j]) + b2f(k2[l][j]);
      float eo = __expf(q * k);  // k-scale folded into k
      ex[l * 8 + j] = eo;
      sum += eo;
    }
  const float rs = valid ? (ew / sum) : 0.f;
#pragma unroll
  for (int l = 0; l < NL; ++l) {
#pragma unroll
    for (int g2 = 0; g2 < 2; ++g2) {
      f32x4 o;
#pragma unroll
      for (int j2 = 0; j2 < 4; ++j2) {
        int j = g2 * 4 + j2;
        o[j2] = ex[l * 8 + j] * rs * (b2f(v1[l][j]) + b2f(v2[l][j]));
      }
      int g = l * 2 + g2;
      int pch = (g * 8 + head + e) & PM;
      *reinterpret_cast<f32x4*>(&ctx[e * O + pch * 4]) = o;
    }
  }
  __syncthreads();

  {
    constexpr int GRP = 512 / O;
    constexpr int EPT = 64 / GRP;
    const int hs2 = t & 7;
    const int cs = (t >> 3) & (HS - 1);
    const int colA = hs2 * HS + cs;
    const int seg0 = (t / O) * EPT;
    const int inv = (cs >> 2) * 8 + hs2;
    const int js = cs & 3;
    float run = 0.f;
#pragma unroll
    for (int i = 0; i < EPT; ++i) {
      int ee = seg0 + i;
      int pch = (inv + ee) & PM;
      run += ctx[ee * O + pch * 4 + js];
      bool bound = (i == EPT - 1) || (dstL[ee + 1] != dstL[ee]);
      if (bound) {
        atomicAdd(&s[(size_t)dstL[ee] * O + colA], run);
        run = 0.f;
      }
    }
  }
}

// ---------------- conversions / finalize ----------------
__global__ void f32_to_bf16(const float* __restrict__ in, unsigned short* __restrict__ out,
                            int n8) {
  int i = blockIdx.x * blockDim.x + threadIdx.x;
  if (i >= n8) return;
  float4 a = reinterpret_cast<const float4*>(in)[2 * i];
  float4 b = reinterpret_cast<const float4*>(in)[2 * i + 1];
  uint4 o;
  o.x = (unsigned)f2bf(a.x) | ((unsigned)f2bf(a.y) << 16);
  o.y = (unsigned)f2bf(a.z) | ((unsigned)f2bf(a.w) << 16);
  o.z = (unsigned)f2bf(b.x) | ((unsigned)f2bf(b.y) << 16);
  o.w = (unsigned)f2bf(b.z) | ((unsigned)f2bf(b.w) << 16);
  reinterpret_cast<uint4*>(out)[i] = o;
}

__global__ void finalize_relu_f32bf16(float* __restrict__ s, const int* __restrict__ rowptr,
                                      unsigned short* __restrict__ xbo, int total4, int Odiv4) {
  int i = blockIdx.x * blockDim.x + threadIdx.x;
  if (i >= total4) return;
  int node = i / Odiv4;
  float c = fmaxf((float)(rowptr[node + 1] - rowptr[node]), 1.0f);
  float4 v = reinterpret_cast<float4*>(s)[i];
  v.x = fmaxf(v.x / c, 0.f);
  v.y = fmaxf(v.y / c, 0.f);
  v.z = fmaxf(v.z / c, 0.f);
  v.w = fmaxf(v.w / c, 0.f);
  reinterpret_cast<float4*>(s)[i] = v;
  ushort4 o = make_ushort4(f2bf(v.x), f2bf(v.y), f2bf(v.z), f2bf(v.w));
  reinterpret_cast<ushort4*>(xbo)[i] = o;
}

__global__ void finalize_relu_bf16(const float* __restrict__ s, const int* __restrict__ rowptr,
                                   unsigned short* __restrict__ xbo, int total4, int Odiv4) {
  int i = blockIdx.x * blockDim.x + threadIdx.x;
  if (i >= total4) return;
  int node = i / Odiv4;
  float c = fmaxf((float)(rowptr[node + 1] - rowptr[node]), 1.0f);
  float4 v = reinterpret_cast<const float4*>(s)[i];
  ushort4 o = make_ushort4(f2bf(fmaxf(v.x / c, 0.f)), f2bf(fmaxf(v.y / c, 0.f)),
                           f2bf(fmaxf(v.z / c, 0.f)), f2bf(fmaxf(v.w / c, 0.f)));
  reinterpret_cast<ushort4*>(xbo)[i] = o;
}

__global__ void finalize_add_relu(float* __restrict__ out, const float* __restrict__ x0,
                                  const int* __restrict__ rowptr, int total4, int Odiv4) {
  int i = blockIdx.x * blockDim.x + threadIdx.x;
  if (i >= total4) return;
  int node = i / Odiv4;
  float c = fmaxf((float)(rowptr[node + 1] - rowptr[node]), 1.0f);
  float4 v = reinterpret_cast<float4*>(out)[i];
  float4 r = reinterpret_cast<const float4*>(x0)[i];
  v.x = fmaxf(v.x / c + r.x, 0.f);
  v.y = fmaxf(v.y / c + r.y, 0.f);
  v.z = fmaxf(v.z / c + r.z, 0.f);
  v.w = fmaxf(v.w / c + r.w, 0.f);
  reinterpret_cast<float4*>(out)[i] = v;
}

extern "C" void kernel_launch(void* const* d_in, const int* in_sizes, int n_in,
                              void* d_out, int out_size, void* d_ws, size_t ws_size,
                              hipStream_t stream) {
  const float* x = (const float*)d_in[0];
  const int* e0 = (const int*)d_in[1];
  const int* e1 = (const int*)d_in[2];
  const int* e2 = (const int*)d_in[3];
  const float* wq0 = (const float*)d_in[5];
  const float* bq0 = (const float*)d_in[6];
  const float* wk0 = (const float*)d_in[7];
  const float* bk0 = (const float*)d_in[8];
  const float* wv0 = (const float*)d_in[9];
  const float* bv0 = (const float*)d_in[10];
  const float* wq1 = (const float*)d_in[11];
  const float* bq1 = (const float*)d_in[12];
  const float* wk1 = (const float*)d_in[13];
  const float* bk1 = (const float*)d_in[14];
  const float* wv1 = (const float*)d_in[15];
  const float* bv1 = (const float*)d_in[16];
  const float* wq2 = (const float*)d_in[17];
  const float* bq2 = (const float*)d_in[18];
  const float* wk2 = (const float*)d_in[19];
  const float* bk2 = (const float*)d_in[20];
  const float* wv2 = (const float*)d_in[21];
  const float* bv2 = (const float*)d_in[22];

  const int N = in_sizes[0] / 128;  // 50000
  const int E = in_sizes[1] / 2;    // 500000
  const int NBLK = (N + 255) / 256;
  const int NP = NBLK * 256;
  const int RP = NP + 256;
  const float SC16 = 0.25f;
  const float SC8 = 0.35355339059327373f;

  // ---- workspace carve-up ----
  unsigned short* wp0 = (unsigned short*)d_ws;       // 98304 shorts
  unsigned short* wp1 = wp0 + 98304;                 // 49152
  unsigned short* wp2 = wp1 + 49152;                 // 49152
  float* bias0 = (float*)(wp2 + 49152);              // 768
  float* bias1 = bias0 + 768;                        // 384
  float* bias2 = bias1 + 384;                        // 768
  unsigned short* xb = (unsigned short*)(bias2 + 768);  // N*128
  unsigned short* Y1 = xb + (size_t)N * 128;         // N*384
  unsigned short* Y2 = Y1 + (size_t)N * 384;         // N*384
  float* s0 = (float*)(Y2 + (size_t)N * 384);        // N*128
  float* s1 = s0 + (size_t)N * 128;                  // N*64
  int* hist = (int*)(s1 + (size_t)N * 64);           // 3*NP
  int* excl = hist + 3 * (size_t)NP;                 // 3*NP
  int* bsum = excl + 3 * (size_t)NP;                 // 768
  int* rowptr = bsum + 768;                          // 3*RP
  int* rank = rowptr + 3 * (size_t)RP;               // 3*E
  long long* pairs = (long long*)(rank + 3 * (size_t)E + 2);  // 3*E (8B aligned)

  hipMemsetAsync(hist, 0, 3 * (size_t)NP * sizeof(int), stream);
  hipMemsetAsync(s0, 0, (size_t)N * 192 * sizeof(float), stream);
  hipMemsetAsync(d_out, 0, (size_t)out_size * sizeof(float), stream);

  pack_weights6<<<48, 256, 0, stream>>>(wq0, wk0, wv0, wp0, 128, 128, SC16);
  pack_weights6<<<24, 256, 0, stream>>>(wq1, wk1, wv1, wp1, 128, 64, SC8);
  pack_weights6<<<24, 256, 0, stream>>>(wq2, wk2, wv2, wp2, 64, 128, SC16);
  pack_bias<<<3, 256, 0, stream>>>(bq0, bk0, bv0, SC16, 128, bias0);
  pack_bias<<<2, 256, 0, stream>>>(bq1, bk1, bv1, SC8, 64, bias1);
  pack_bias<<<3, 256, 0, stream>>>(bq2, bk2, bv2, SC16, 128, bias2);
  f32_to_bf16<<<(N * 16 + 255) / 256, 256, 0, stream>>>(x, xb, N * 16);

  const int EB256 = (E + 255) / 256;
  hist3<<<EB256, 256, 0, stream>>>(e0, e1, e2, E, hist, rank, NP);
  scan_pass1<<<dim3(NBLK, 3), 256, 0, stream>>>(hist, excl, bsum, N, NP);
  scan_pass2<<<dim3(1, 3), 256, 0, stream>>>(bsum, NBLK);
  scan_pass3<<<dim3(NBLK, 3), 256, 0, stream>>>(excl, bsum, rowptr, N, NP, RP, E);
  scatter3<<<dim3(EB256, 3), 256, 0, stream>>>(e0, e1, e2, E, rowptr, rank, pairs, NP, RP);

  const int NT = (N + 63) / 64;
  const int EBK = (E + 63) / 64;
  const int EGRID = 8 * ((EBK + 7) / 8);  // bijective XCD swizzle grid

  // Layer 0: IN=128, O=128, HS=16
  node_gemm<128, 128><<<dim3(NT, 6), 256, 0, stream>>>(xb, N, wp0, bias0, Y1, Y2);
  edge_attn_kernel<128, 16><<<EGRID, 512, 0, stream>>>(Y1, Y2, (const int2*)pairs, E, s0);
  finalize_relu_f32bf16<<<(N * 32 + 255) / 256, 256, 0, stream>>>(s0, rowptr, xb, N * 32, 32);
  // Layer 1: IN=128, O=64, HS=8
  node_gemm<128, 64><<<dim3(NT, 3), 256, 0, stream>>>(xb, N, wp1, bias1, Y1, Y2);
  edge_attn_kernel<64, 8><<<EGRID, 512, 0, stream>>>(Y1, Y2, (const int2*)(pairs + E), E, s1);
  finalize_relu_bf16<<<(N * 16 + 255) / 256, 256, 0, stream>>>(s1, rowptr + RP, xb, N * 16, 16);
  // Layer 2: IN=64, O=128, HS=16 -> accumulate into d_out
  node_gemm<64, 128><<<dim3(NT, 6), 256, 0, stream>>>(xb, N, wp2, bias2, Y1, Y2);
  edge_attn_kernel<128, 16><<<EGRID, 512, 0, stream>>>(Y1, Y2, (const int2*)(pairs + 2 * (size_t)E),
                                                       E, (float*)d_out);
  finalize_add_relu<<<(N * 32 + 255) / 256, 256, 0, stream>>>((float*)d_out, s0, rowptr + 2 * RP,
                                                              N * 32, 32);
}